// Round 7
// baseline (49.139 us; speedup 1.0000x reference)
//
#include <hip/hip_runtime.h>
#include <math.h>

// Problem constants (compile-time; from reference setup_inputs)
#define BATCH     65536
#define NNBR      8
#define DIM       16
#define HALF_L2W  5.0e-5f            // 0.5 * L2_WEIGHT

#define BLOCK     256
#define GRIDB     1024               // 64 rows/block * 1024 = 65536 rows
#define STH       (GRIDB * BLOCK)    // 262144 streaming threads
#define ROWS_PB   64

// table sizes in float4 units
#define N_E4      8000000            // 2,000,000 * 16 / 4
#define N_U4      400000             // 100,000 * 16 / 4
#define N_R4      256                // 64 * 16 / 4

#define E_ITERS   (N_E4 / STH)             // 30
#define E_TAIL    (N_E4 - E_ITERS * STH)   // 135680
#define U_TAIL    (N_U4 - STH)             // 137856

#define PRE_ITERS 8                  // stream iters issued before DMA gathers

__device__ __forceinline__ float sq4(float4 v) {
    return v.x * v.x + v.y * v.y + v.z * v.z + v.w * v.w;
}

#if defined(__has_builtin)
#if __has_builtin(__builtin_amdgcn_global_load_lds)
#define HAS_GLL 1
#endif
#endif

#ifdef HAS_GLL
// async global->LDS DMA: per-lane global src, wave-uniform LDS base, lane*16B placement
__device__ __forceinline__ void gload16(const void* gsrc, void* lds_base) {
    __builtin_amdgcn_global_load_lds(
        (__attribute__((address_space(1))) void*)gsrc,
        (__attribute__((address_space(3))) void*)lds_base,
        16, 0, 0);
}
#endif

// ws layout: ws[2*b] = l2 partial, ws[2*b+1] = bce partial (plain stores, no init)
__global__ void __launch_bounds__(BLOCK)
fused_kernel(const float4* __restrict__ ue4,
             const float4* __restrict__ ee4,
             const float4* __restrict__ re4,
             const float*  __restrict__ W,      // [D][D]
             const float4* __restrict__ b4,     // [D/4]
             const float*  __restrict__ labels,
             const int*    __restrict__ uidx,
             const int*    __restrict__ iidx,
             const int4*   __restrict__ adjE4,  // [N_ENTITY][2] int4
             const int4*   __restrict__ adjR4,
             float* __restrict__ ws) {
    __shared__ float  sWT[DIM * DIM];          // sWT[j*16+i] = W[i][j]
    __shared__ float4 sbias[DIM / 4];
    __shared__ float4 gbuf[4][10][64];         // 40 KB: per-wave gather buffers
    __shared__ float  sred[8];

    sWT[threadIdx.x] = W[(threadIdx.x & 15) * DIM + (threadIdx.x >> 4)];
    if (threadIdx.x < DIM / 4) sbias[threadIdx.x] = b4[threadIdx.x];
    __syncthreads();   // early barrier (cheap drain: only W loads outstanding)

    const int lane4 = threadIdx.x & 3;          // dim-quad index
    const int l     = threadIdx.x & 63;         // lane in wave
    const int w     = threadIdx.x >> 6;         // wave id 0..3
    const int row   = blockIdx.x * ROWS_PB + (threadIdx.x >> 2);
    const int tid_g = blockIdx.x * BLOCK + threadIdx.x;

    // ---- row-index loads (coalesced) + dependent adj loads ----
    const int ui = uidx[row];
    const int it = iidx[row];
    const float y = labels[row];
    const int4 a0 = adjE4[it * 2], a1 = adjE4[it * 2 + 1];
    const int4 r0 = adjR4[it * 2], r1 = adjR4[it * 2 + 1];
    const int ne[NNBR] = {a0.x, a0.y, a0.z, a0.w, a1.x, a1.y, a1.z, a1.w};
    const int nr[NNBR] = {r0.x, r0.y, r0.z, r0.w, r1.x, r1.y, r1.z, r1.w};

    // ---- stream phase 1: first PRE_ITERS iters (hides adj-load latency) ----
    float l2 = 0.0f;
    const float4* p = ee4 + tid_g;
    #pragma unroll
    for (int k = 0; k < PRE_ITERS; ++k) l2 += sq4(p[k * STH]);

    // ---- issue gather DMA into LDS (zero VGPR cost, rides the VMEM queue) ----
#ifdef HAS_GLL
    #pragma unroll
    for (int k = 0; k < NNBR; ++k)
        gload16(ee4 + (size_t)ne[k] * 4 + lane4, &gbuf[w][k][0]);
    gload16(ee4 + (size_t)it * 4 + lane4, &gbuf[w][8][0]);
    gload16(ue4 + (size_t)ui * 4 + lane4, &gbuf[w][9][0]);
#else
    #pragma unroll
    for (int k = 0; k < NNBR; ++k)
        gbuf[w][k][l] = ee4[(size_t)ne[k] * 4 + lane4];
    gbuf[w][8][l] = ee4[(size_t)it * 4 + lane4];
    gbuf[w][9][l] = ue4[(size_t)ui * 4 + lane4];
#endif

    // ---- stream phase 2: remaining iters + tails ----
    #pragma unroll
    for (int k = PRE_ITERS; k < E_ITERS; ++k) l2 += sq4(p[k * STH]);
    if (tid_g < E_TAIL) l2 += sq4(p[E_ITERS * STH]);
    l2 += sq4(ue4[tid_g]);
    if (tid_g < U_TAIL) l2 += sq4(ue4[tid_g + STH]);
    if (tid_g < N_R4)   l2 += sq4(re4[tid_g]);

    // ---- wait for gather DMA, consume from LDS ----
#ifdef HAS_GLL
    asm volatile("s_waitcnt vmcnt(0)" ::: "memory");
#endif
    const float4 u4  = gbuf[w][9][l];
    const float4 sv4 = gbuf[w][8][l];

    float sc[NNBR];
    float4 nv[NNBR];
    #pragma unroll
    for (int k = 0; k < NNBR; ++k) {
        const float4 rv = re4[nr[k] * 4 + lane4];   // 4 KB table, cache-hot
        nv[k] = gbuf[w][k][l];
        float s = u4.x * rv.x + u4.y * rv.y + u4.z * rv.z + u4.w * rv.w;
        s += __shfl_xor(s, 1, 4);
        s += __shfl_xor(s, 2, 4);
        sc[k] = s * (1.0f / 16.0f);
    }

    float m = sc[0];
    #pragma unroll
    for (int k = 1; k < NNBR; ++k) m = fmaxf(m, sc[k]);
    float e[NNBR], den = 0.0f;
    #pragma unroll
    for (int k = 0; k < NNBR; ++k) { e[k] = __expf(sc[k] - m); den += e[k]; }
    const float inv = 1.0f / den;

    float4 agg = make_float4(0.f, 0.f, 0.f, 0.f);
    #pragma unroll
    for (int k = 0; k < NNBR; ++k) {
        agg.x += e[k] * nv[k].x; agg.y += e[k] * nv[k].y;
        agg.z += e[k] * nv[k].z; agg.w += e[k] * nv[k].w;
    }

    float4 x4;
    x4.x = sv4.x + agg.x * inv; x4.y = sv4.y + agg.y * inv;
    x4.z = sv4.z + agg.z * inv; x4.w = sv4.w + agg.w * inv;

    // broadcast all 16 x_j across the 4-lane group
    float xall[DIM];
    #pragma unroll
    for (int src = 0; src < 4; ++src) {
        xall[4 * src + 0] = __shfl(x4.x, src, 4);
        xall[4 * src + 1] = __shfl(x4.y, src, 4);
        xall[4 * src + 2] = __shfl(x4.z, src, 4);
        xall[4 * src + 3] = __shfl(x4.w, src, 4);
    }

    const float4* sWT4 = (const float4*)sWT;
    float4 acc = sbias[lane4];
    #pragma unroll
    for (int j = 0; j < DIM; ++j) {
        const float4 wv = sWT4[j * 4 + lane4];
        acc.x += xall[j] * wv.x; acc.y += xall[j] * wv.y;
        acc.z += xall[j] * wv.z; acc.w += xall[j] * wv.w;
    }
    float4 item;
    item.x = tanhf(acc.x); item.y = tanhf(acc.y);
    item.z = tanhf(acc.z); item.w = tanhf(acc.w);

    float lg = u4.x * item.x + u4.y * item.y + u4.z * item.z + u4.w * item.w;
    lg += __shfl_xor(lg, 1, 4);
    lg += __shfl_xor(lg, 2, 4);

    float bce = 0.0f;
    if (lane4 == 0) {
        bce = fmaxf(lg, 0.0f) - lg * y + log1pf(__expf(-fabsf(lg)));
    }

    // ---- block reduction of {l2, bce} ----
    #pragma unroll
    for (int o = 32; o > 0; o >>= 1) {
        bce += __shfl_down(bce, o);
        l2  += __shfl_down(l2, o);
    }
    if ((threadIdx.x & 63) == 0) { sred[w] = l2; sred[4 + w] = bce; }
    __syncthreads();
    if (threadIdx.x == 0) {
        ws[2 * blockIdx.x]     = sred[0] + sred[1] + sred[2] + sred[3];
        ws[2 * blockIdx.x + 1] = sred[4] + sred[5] + sred[6] + sred[7];
    }
}

__global__ void __launch_bounds__(256)
finalize_kernel(const float* __restrict__ ws, float* __restrict__ out) {
    float l2 = 0.0f, bce = 0.0f;
    #pragma unroll
    for (int k = 0; k < GRIDB / 256; ++k) {        // 4 iters
        const int i = threadIdx.x + k * 256;
        l2  += ws[2 * i];
        bce += ws[2 * i + 1];
    }
    #pragma unroll
    for (int o = 32; o > 0; o >>= 1) {
        l2  += __shfl_down(l2, o);
        bce += __shfl_down(bce, o);
    }
    __shared__ float sred[8];
    const int wid = threadIdx.x >> 6;
    if ((threadIdx.x & 63) == 0) { sred[wid] = l2; sred[4 + wid] = bce; }
    __syncthreads();
    if (threadIdx.x == 0) {
        const float l2t  = sred[0] + sred[1] + sred[2] + sred[3];
        const float bcet = sred[4] + sred[5] + sred[6] + sred[7];
        out[0] = bcet * (1.0f / (float)BATCH) + HALF_L2W * l2t;
    }
}

extern "C" void kernel_launch(void* const* d_in, const int* in_sizes, int n_in,
                              void* d_out, int out_size, void* d_ws, size_t ws_size,
                              hipStream_t stream) {
    const float4* ue4    = (const float4*)d_in[0];
    const float4* ee4    = (const float4*)d_in[1];
    const float4* re4    = (const float4*)d_in[2];
    const float*  W      = (const float*)d_in[3];
    const float4* b4     = (const float4*)d_in[4];
    const float*  labels = (const float*)d_in[5];
    const int*    uidx   = (const int*)d_in[6];
    const int*    iidx   = (const int*)d_in[7];
    const int4*   adjE4  = (const int4*)d_in[8];
    const int4*   adjR4  = (const int4*)d_in[9];

    float* ws  = (float*)d_ws;
    float* out = (float*)d_out;

    fused_kernel<<<GRIDB, BLOCK, 0, stream>>>(
        ue4, ee4, re4, W, b4, labels, uidx, iidx, adjE4, adjR4, ws);

    finalize_kernel<<<1, 256, 0, stream>>>(ws, out);
}

// Round 9
// 44.240 us; speedup vs baseline: 1.1107x; 1.1107x over previous
//
#include <hip/hip_runtime.h>
#include <math.h>

// Problem constants (compile-time; from reference setup_inputs)
#define BATCH     65536
#define NNBR      8
#define DIM       16
#define HALF_L2W  5.0e-5f            // 0.5 * L2_WEIGHT

#define BLOCK     256
#define GRIDB     3072               // 2048 stream blocks + 1024 row blocks (2:1 interleave)
#define N_SBLK    2048
#define STH       (N_SBLK * BLOCK)   // 524288 streaming threads
#define ROWS_PB   64                 // rows per row-block (4 lanes/row)

// table sizes in float4 units
#define N_E4      8000000            // 2,000,000 * 16 / 4
#define N_U4      400000             // 100,000 * 16 / 4
#define N_R4      256                // 64 * 16 / 4

#define E_ITERS   (N_E4 / STH)             // 15
#define E_TAIL    (N_E4 - E_ITERS * STH)   // 135680

// clang native vector type accepted by __builtin_nontemporal_load
typedef float vfloat4 __attribute__((ext_vector_type(4)));

__device__ __forceinline__ float sq4(float4 v) {
    return v.x * v.x + v.y * v.y + v.z * v.z + v.w * v.w;
}
__device__ __forceinline__ float sq4v(vfloat4 v) {
    return v.x * v.x + v.y * v.y + v.z * v.z + v.w * v.w;
}
__device__ __forceinline__ float nt_sq4(const float4* p) {
    return sq4v(__builtin_nontemporal_load((const vfloat4*)p));
}

// ws layout: ws[2*b] = l2 partial, ws[2*b+1] = bce partial (plain stores, no init)
__global__ void __launch_bounds__(BLOCK, 4)
fused_kernel(const float4* __restrict__ ue4,
             const float4* __restrict__ ee4,
             const float4* __restrict__ re4,
             const float*  __restrict__ W,      // [D][D]
             const float4* __restrict__ b4,     // [D/4]
             const float*  __restrict__ labels,
             const int*    __restrict__ uidx,
             const int*    __restrict__ iidx,
             const int4*   __restrict__ adjE4,  // [N_ENTITY][2] int4
             const int4*   __restrict__ adjR4,
             float* __restrict__ ws) {
    float l2 = 0.0f, bce = 0.0f;

    const int bid  = blockIdx.x;
    const int tri  = bid % 3;            // 0,1 = stream; 2 = row (block-uniform)

    if (tri != 2) {
        // ---------------- streaming L2 sum-of-squares (non-temporal) ----------------
        const int rid = (bid / 3) * 2 + tri;          // 0..2047
        const int tid = rid * BLOCK + threadIdx.x;
        const float4* p = ee4 + tid;
        #pragma unroll
        for (int k = 0; k < E_ITERS; ++k) l2 += nt_sq4(p + k * STH);
        if (tid < E_TAIL) l2 += nt_sq4(p + E_ITERS * STH);
        if (tid < N_U4)   l2 += sq4(ue4[tid]);
        if (tid < N_R4)   l2 += sq4(re4[tid]);
    } else {
        // ---------------- KGCN row work: 4 lanes/row, 64 rows/block ----------------
        __shared__ float sWT[DIM * DIM];       // sWT[j*16+i] = W[i][j]
        __shared__ float4 sbias[DIM / 4];
        if (threadIdx.x < DIM * DIM)
            sWT[threadIdx.x] = W[(threadIdx.x & 15) * DIM + (threadIdx.x >> 4)];
        if (threadIdx.x < DIM / 4) sbias[threadIdx.x] = b4[threadIdx.x];
        __syncthreads();

        const int rid   = bid / 3;             // 0..1023
        const int lane4 = threadIdx.x & 3;     // dim-quad index
        const int row   = rid * ROWS_PB + (threadIdx.x >> 2);

        const int ui = uidx[row];
        const int it = iidx[row];
        const float4 u4  = ue4[ui * 4 + lane4];
        const float4 sv4 = ee4[it * 4 + lane4];
        const int4 a0 = adjE4[it * 2], a1 = adjE4[it * 2 + 1];
        const int4 r0 = adjR4[it * 2], r1 = adjR4[it * 2 + 1];

        const int ne[NNBR] = {a0.x, a0.y, a0.z, a0.w, a1.x, a1.y, a1.z, a1.w};
        const int nr[NNBR] = {r0.x, r0.y, r0.z, r0.w, r1.x, r1.y, r1.z, r1.w};

        float4 nv[NNBR];
        float sc[NNBR];
        #pragma unroll
        for (int k = 0; k < NNBR; ++k) {
            const float4 rv = re4[nr[k] * 4 + lane4];  // 64 relations -> cache-hot
            nv[k] = ee4[ne[k] * 4 + lane4];            // random gather
            float s = u4.x * rv.x + u4.y * rv.y + u4.z * rv.z + u4.w * rv.w;
            s += __shfl_xor(s, 1, 4);
            s += __shfl_xor(s, 2, 4);
            sc[k] = s * (1.0f / 16.0f);
        }

        float m = sc[0];
        #pragma unroll
        for (int k = 1; k < NNBR; ++k) m = fmaxf(m, sc[k]);
        float e[NNBR], den = 0.0f;
        #pragma unroll
        for (int k = 0; k < NNBR; ++k) { e[k] = __expf(sc[k] - m); den += e[k]; }
        const float inv = 1.0f / den;

        float4 agg = make_float4(0.f, 0.f, 0.f, 0.f);
        #pragma unroll
        for (int k = 0; k < NNBR; ++k) {
            agg.x += e[k] * nv[k].x; agg.y += e[k] * nv[k].y;
            agg.z += e[k] * nv[k].z; agg.w += e[k] * nv[k].w;
        }

        float4 x4;
        x4.x = sv4.x + agg.x * inv; x4.y = sv4.y + agg.y * inv;
        x4.z = sv4.z + agg.z * inv; x4.w = sv4.w + agg.w * inv;

        float xall[DIM];
        #pragma unroll
        for (int src = 0; src < 4; ++src) {
            xall[4 * src + 0] = __shfl(x4.x, src, 4);
            xall[4 * src + 1] = __shfl(x4.y, src, 4);
            xall[4 * src + 2] = __shfl(x4.z, src, 4);
            xall[4 * src + 3] = __shfl(x4.w, src, 4);
        }

        const float4* sWT4 = (const float4*)sWT;
        float4 acc = sbias[lane4];
        #pragma unroll
        for (int j = 0; j < DIM; ++j) {
            const float4 wv = sWT4[j * 4 + lane4];
            acc.x += xall[j] * wv.x; acc.y += xall[j] * wv.y;
            acc.z += xall[j] * wv.z; acc.w += xall[j] * wv.w;
        }
        float4 item;
        item.x = tanhf(acc.x); item.y = tanhf(acc.y);
        item.z = tanhf(acc.z); item.w = tanhf(acc.w);

        float lg = u4.x * item.x + u4.y * item.y + u4.z * item.z + u4.w * item.w;
        lg += __shfl_xor(lg, 1, 4);
        lg += __shfl_xor(lg, 2, 4);

        if (lane4 == 0) {
            const float y = labels[row];
            bce = fmaxf(lg, 0.0f) - lg * y + log1pf(__expf(-fabsf(lg)));
        }
    }

    // ---------------- block reduction of {l2, bce} ----------------
    #pragma unroll
    for (int o = 32; o > 0; o >>= 1) {
        bce += __shfl_down(bce, o);
        l2  += __shfl_down(l2, o);
    }
    __shared__ float sred[8];  // 4 waves x {l2, bce}
    const int wid = threadIdx.x >> 6;
    if ((threadIdx.x & 63) == 0) { sred[wid] = l2; sred[4 + wid] = bce; }
    __syncthreads();
    if (threadIdx.x == 0) {
        ws[2 * blockIdx.x]     = sred[0] + sred[1] + sred[2] + sred[3];
        ws[2 * blockIdx.x + 1] = sred[4] + sred[5] + sred[6] + sred[7];
    }
}

__global__ void __launch_bounds__(256)
finalize_kernel(const float* __restrict__ ws, float* __restrict__ out) {
    float l2 = 0.0f, bce = 0.0f;
    #pragma unroll
    for (int k = 0; k < GRIDB / 256; ++k) {        // 12 iters
        const int i = threadIdx.x + k * 256;
        l2  += ws[2 * i];
        bce += ws[2 * i + 1];
    }
    #pragma unroll
    for (int o = 32; o > 0; o >>= 1) {
        l2  += __shfl_down(l2, o);
        bce += __shfl_down(bce, o);
    }
    __shared__ float sred[8];
    const int wid = threadIdx.x >> 6;
    if ((threadIdx.x & 63) == 0) { sred[wid] = l2; sred[4 + wid] = bce; }
    __syncthreads();
    if (threadIdx.x == 0) {
        const float l2t  = sred[0] + sred[1] + sred[2] + sred[3];
        const float bcet = sred[4] + sred[5] + sred[6] + sred[7];
        out[0] = bcet * (1.0f / (float)BATCH) + HALF_L2W * l2t;
    }
}

extern "C" void kernel_launch(void* const* d_in, const int* in_sizes, int n_in,
                              void* d_out, int out_size, void* d_ws, size_t ws_size,
                              hipStream_t stream) {
    const float4* ue4    = (const float4*)d_in[0];
    const float4* ee4    = (const float4*)d_in[1];
    const float4* re4    = (const float4*)d_in[2];
    const float*  W      = (const float*)d_in[3];
    const float4* b4     = (const float4*)d_in[4];
    const float*  labels = (const float*)d_in[5];
    const int*    uidx   = (const int*)d_in[6];
    const int*    iidx   = (const int*)d_in[7];
    const int4*   adjE4  = (const int4*)d_in[8];
    const int4*   adjR4  = (const int4*)d_in[9];

    float* ws  = (float*)d_ws;
    float* out = (float*)d_out;

    fused_kernel<<<GRIDB, BLOCK, 0, stream>>>(
        ue4, ee4, re4, W, b4, labels, uidx, iidx, adjE4, adjR4, ws);

    finalize_kernel<<<1, 256, 0, stream>>>(ws, out);
}

// Round 10
// 43.526 us; speedup vs baseline: 1.1289x; 1.0164x over previous
//
#include <hip/hip_runtime.h>
#include <math.h>

// Problem constants (compile-time; from reference setup_inputs)
#define BATCH     65536
#define NNBR      8
#define DIM       16
#define HALF_L2W  5.0e-5f            // 0.5 * L2_WEIGHT

#define BLOCK     256
#define GRID      2048               // 1024 stream blocks + 1024 row blocks, parity-interleaved
#define N_SBLK    1024
#define STH       (N_SBLK * BLOCK)   // 262144 streaming threads
#define ROWS_PB   64                 // rows per row-block (4 lanes/row)

// table sizes in float4 units
#define N_E4      8000000            // 2,000,000 * 16 / 4
#define N_U4      400000             // 100,000 * 16 / 4
#define N_R4      256                // 64 * 16 / 4

#define E_ITERS   (N_E4 / STH)             // 30
#define E_TAIL    (N_E4 - E_ITERS * STH)   // 135680
#define U_TAIL    (N_U4 - STH)             // 137856

__device__ __forceinline__ float sq4(float4 v) {
    return v.x * v.x + v.y * v.y + v.z * v.z + v.w * v.w;
}

// ws layout: ws[2*b] = l2 partial, ws[2*b+1] = bce partial (plain stores, no init)
__global__ void __launch_bounds__(BLOCK, 4)
fused_kernel(const float4* __restrict__ ue4,
             const float4* __restrict__ ee4,
             const float4* __restrict__ re4,
             const float*  __restrict__ W,      // [D][D]
             const float4* __restrict__ b4,     // [D/4]
             const float*  __restrict__ labels,
             const int*    __restrict__ uidx,
             const int*    __restrict__ iidx,
             const int4*   __restrict__ adjE4,  // [N_ENTITY][2] int4
             const int4*   __restrict__ adjR4,
             float* __restrict__ ws) {
    float l2 = 0.0f, bce = 0.0f;

    const int role = blockIdx.x & 1;     // 0 = stream, 1 = row (block-uniform)
    const int rid  = blockIdx.x >> 1;    // role-local block id, 0..1023

    if (role == 0) {
        // ---------------- streaming L2 sum-of-squares ----------------
        const int tid = rid * BLOCK + threadIdx.x;
        const float4* p = ee4 + tid;
        #pragma unroll
        for (int k = 0; k < E_ITERS; ++k) l2 += sq4(p[k * STH]);
        if (tid < E_TAIL) l2 += sq4(p[E_ITERS * STH]);
        l2 += sq4(ue4[tid]);
        if (tid < U_TAIL) l2 += sq4(ue4[tid + STH]);
        if (tid < N_R4)   l2 += sq4(re4[tid]);
    } else {
        // ---------------- KGCN row work: 4 lanes/row, 64 rows/block ----------------
        __shared__ float sWT[DIM * DIM];       // sWT[j*16+i] = W[i][j]
        __shared__ float4 sb4[DIM / 4];
        if (threadIdx.x < DIM * DIM)
            sWT[threadIdx.x] = W[(threadIdx.x & 15) * DIM + (threadIdx.x >> 4)];
        if (threadIdx.x < DIM / 4) sb4[threadIdx.x] = b4[threadIdx.x];
        __syncthreads();

        const int lane4 = threadIdx.x & 3;     // dim-quad index
        const int rgrp  = threadIdx.x >> 2;    // row within block
        const int row   = rid * ROWS_PB + rgrp;

        const int ui = uidx[row];
        const int it = iidx[row];
        const float4 u4  = ue4[ui * 4 + lane4];
        const float4 sv4 = ee4[it * 4 + lane4];
        const int4 a0 = adjE4[it * 2], a1 = adjE4[it * 2 + 1];
        const int4 r0 = adjR4[it * 2], r1 = adjR4[it * 2 + 1];

        const int ne[NNBR] = {a0.x, a0.y, a0.z, a0.w, a1.x, a1.y, a1.z, a1.w};
        const int nr[NNBR] = {r0.x, r0.y, r0.z, r0.w, r1.x, r1.y, r1.z, r1.w};

        float4 nv[NNBR];
        float sc[NNBR];
        #pragma unroll
        for (int k = 0; k < NNBR; ++k) {
            const float4 rv = re4[nr[k] * 4 + lane4];  // 64 relations -> cache-hot
            nv[k] = ee4[ne[k] * 4 + lane4];            // random gather
            float s = u4.x * rv.x + u4.y * rv.y + u4.z * rv.z + u4.w * rv.w;
            s += __shfl_xor(s, 1, 4);
            s += __shfl_xor(s, 2, 4);
            sc[k] = s * (1.0f / 16.0f);
        }

        float m = sc[0];
        #pragma unroll
        for (int k = 1; k < NNBR; ++k) m = fmaxf(m, sc[k]);
        float e[NNBR], den = 0.0f;
        #pragma unroll
        for (int k = 0; k < NNBR; ++k) { e[k] = __expf(sc[k] - m); den += e[k]; }
        const float inv = 1.0f / den;

        float4 agg = make_float4(0.f, 0.f, 0.f, 0.f);
        #pragma unroll
        for (int k = 0; k < NNBR; ++k) {
            agg.x += e[k] * nv[k].x; agg.y += e[k] * nv[k].y;
            agg.z += e[k] * nv[k].z; agg.w += e[k] * nv[k].w;
        }

        float4 x4;
        x4.x = sv4.x + agg.x * inv; x4.y = sv4.y + agg.y * inv;
        x4.z = sv4.z + agg.z * inv; x4.w = sv4.w + agg.w * inv;

        float xall[DIM];
        #pragma unroll
        for (int src = 0; src < 4; ++src) {
            xall[4 * src + 0] = __shfl(x4.x, src, 4);
            xall[4 * src + 1] = __shfl(x4.y, src, 4);
            xall[4 * src + 2] = __shfl(x4.z, src, 4);
            xall[4 * src + 3] = __shfl(x4.w, src, 4);
        }

        const float4* sWT4 = (const float4*)sWT;
        float4 acc = sb4[lane4];
        #pragma unroll
        for (int j = 0; j < DIM; ++j) {
            const float4 wv = sWT4[j * 4 + lane4];
            acc.x += xall[j] * wv.x; acc.y += xall[j] * wv.y;
            acc.z += xall[j] * wv.z; acc.w += xall[j] * wv.w;
        }
        float4 item;
        item.x = tanhf(acc.x); item.y = tanhf(acc.y);
        item.z = tanhf(acc.z); item.w = tanhf(acc.w);

        float lg = u4.x * item.x + u4.y * item.y + u4.z * item.z + u4.w * item.w;
        lg += __shfl_xor(lg, 1, 4);
        lg += __shfl_xor(lg, 2, 4);

        if (lane4 == 0) {
            const float y = labels[row];
            bce = fmaxf(lg, 0.0f) - lg * y + log1pf(__expf(-fabsf(lg)));
        }
    }

    // ---------------- block reduction of {l2, bce} ----------------
    #pragma unroll
    for (int o = 32; o > 0; o >>= 1) {
        bce += __shfl_down(bce, o);
        l2  += __shfl_down(l2, o);
    }
    __shared__ float sred[8];  // 4 waves x {l2, bce}
    const int wid = threadIdx.x >> 6;
    if ((threadIdx.x & 63) == 0) { sred[wid] = l2; sred[4 + wid] = bce; }
    __syncthreads();
    if (threadIdx.x == 0) {
        ws[2 * blockIdx.x]     = sred[0] + sred[1] + sred[2] + sred[3];
        ws[2 * blockIdx.x + 1] = sred[4] + sred[5] + sred[6] + sred[7];
    }
}

__global__ void __launch_bounds__(256)
finalize_kernel(const float* __restrict__ ws, float* __restrict__ out) {
    float l2 = 0.0f, bce = 0.0f;
    #pragma unroll
    for (int k = 0; k < GRID / 256; ++k) {
        const int i = threadIdx.x + k * 256;
        l2  += ws[2 * i];
        bce += ws[2 * i + 1];
    }
    #pragma unroll
    for (int o = 32; o > 0; o >>= 1) {
        l2  += __shfl_down(l2, o);
        bce += __shfl_down(bce, o);
    }
    __shared__ float sred[8];
    const int wid = threadIdx.x >> 6;
    if ((threadIdx.x & 63) == 0) { sred[wid] = l2; sred[4 + wid] = bce; }
    __syncthreads();
    if (threadIdx.x == 0) {
        const float l2t  = sred[0] + sred[1] + sred[2] + sred[3];
        const float bcet = sred[4] + sred[5] + sred[6] + sred[7];
        out[0] = bcet * (1.0f / (float)BATCH) + HALF_L2W * l2t;
    }
}

extern "C" void kernel_launch(void* const* d_in, const int* in_sizes, int n_in,
                              void* d_out, int out_size, void* d_ws, size_t ws_size,
                              hipStream_t stream) {
    const float4* ue4    = (const float4*)d_in[0];
    const float4* ee4    = (const float4*)d_in[1];
    const float4* re4    = (const float4*)d_in[2];
    const float*  W      = (const float*)d_in[3];
    const float4* b4     = (const float4*)d_in[4];
    const float*  labels = (const float*)d_in[5];
    const int*    uidx   = (const int*)d_in[6];
    const int*    iidx   = (const int*)d_in[7];
    const int4*   adjE4  = (const int4*)d_in[8];
    const int4*   adjR4  = (const int4*)d_in[9];

    float* ws  = (float*)d_ws;
    float* out = (float*)d_out;

    fused_kernel<<<GRID, BLOCK, 0, stream>>>(
        ue4, ee4, re4, W, b4, labels, uidx, iidx, adjE4, adjR4, ws);

    finalize_kernel<<<1, 256, 0, stream>>>(ws, out);
}